// Round 13
// baseline (235.760 us; speedup 1.0000x reference)
//
#include <hip/hip_runtime.h>

// Problem constants: T=512, B=64, D=1024, fp32.
#define T_DIM 512
#define BD    65536            // B*D floats per time slice
#define K     32               // t-steps per pipeline stage
#define NB    (T_DIM / K)      // 16 stages

__device__ __forceinline__ float sigmoid_fast(float x) {
    // 1 / (1 + e^-x) via hw exp2 + hw rcp (~2 ULP, fine vs f32 reference)
    float e = __expf(-x);
    return __builtin_amdgcn_rcpf(1.0f + e);
}

// Single-pass scan, one thread per (b,d) column — minimum traffic (R10:
// FETCH 65.7MB thanks to harness-restore L3 priming + WRITE 131.6MB).
// R10 was latency-bound (380 cyc/t-step ~ 2.4 loads in flight, VGPR=64).
// Fix: explicit 1-deep software pipeline — prefetch the next 32 loads as a
// cluster (no intervening consumer), then consume the current block.
// Full unroll => all buf indices static (no scratch). __launch_bounds__(128,1)
// lifts the VGPR cap (we want exactly 1 wave/SIMD: 1024 waves on 1024 SIMDs).
__global__ __launch_bounds__(128, 1)
void SumGoalHistory_onepass(const float* __restrict__ goal,
                            const float* __restrict__ init,
                            float* __restrict__ out) {
    const int col = blockIdx.x * 128 + threadIdx.x;   // [0, BD)

    float acc = init[col];
    const float* p = goal + col;
    float*       o = out  + col;

    float buf[2][K];

    // prologue: load block 0
    #pragma unroll
    for (int k = 0; k < K; ++k)
        buf[0][k] = p[(size_t)k * BD];

    #pragma unroll
    for (int b = 0; b < NB; ++b) {
        // prefetch block b+1 (32 independent loads, issued as a cluster;
        // their ~900-cyc HBM latency hides under block b's compute+stores)
        if (b + 1 < NB) {
            #pragma unroll
            for (int k = 0; k < K; ++k)
                buf[(b + 1) & 1][k] = p[(size_t)((b + 1) * K + k) * BD];
        }
        // consume block b
        #pragma unroll
        for (int k = 0; k < K; ++k) {
            acc += buf[b & 1][k];
            // nt: outputs never re-read; don't evict L3-hot goal
            __builtin_nontemporal_store(sigmoid_fast(acc),
                                        o + (size_t)(b * K + k) * BD);
        }
    }

    // final_state written twice: d_out layout = outputs | final | final
    float* fin = out + (size_t)T_DIM * BD;
    fin[col] = acc;
    fin[BD + col] = acc;
}

extern "C" void kernel_launch(void* const* d_in, const int* in_sizes, int n_in,
                              void* d_out, int out_size, void* d_ws, size_t ws_size,
                              hipStream_t stream) {
    const float* goal = (const float*)d_in[0];   // [T, B, D] f32
    const float* init = (const float*)d_in[1];   // [1, B, D] f32
    float* out = (float*)d_out;                  // outputs | final | final

    SumGoalHistory_onepass<<<BD / 128, 128, 0, stream>>>(goal, init, out);
}